// Round 2
// baseline (219.834 us; speedup 1.0000x reference)
//
#include <hip/hip_runtime.h>

// SNNLinear, exact-trajectory i8-digit MFMA. Round 20 = WAVE-BLOCK fusion.
// R19's fused kernel was latency-bound (MfmaUtil 23%, occupancy 14.8%):
// 51 KB LDS -> 3 blocks/CU, 16 barriers/block, and a ~3us serial scan tail
// per block with nothing co-resident to hide it.
// R20: one WAVE per block. Wave = (b, n16): 112m x 16n x 1024k x 4 planes,
// acc[7][4] unchanged. Fragments load DIRECTLY global->VGPR (A8/Bt are
// fragment-tiled: 1 KB chunk = one lane-linear wave fragment). No LDS
// staging, no barriers. LDS = du transpose only (100x16 f64 = 12.8 KB)
// -> 12 blocks/CU resident; each wave's serial scan overlaps 11 other
// waves' MFMA phases (separate pipes). Grid bid = ng*64 + b so same-CU
// waves (bid +- 256) share the A panel in L1/L2.
// Math identical to R19 (passed): exact 0/1 A, 4 balanced base-256 i8
// planes of round(W*2^28), mfma_i32_16x16x64_i8 exact, i64 Horner ->
// exact f64 du -> f64 scan verbatim.
// Outputs: ss[100,64,1024] | mem_out[64,1024] | hat_s[64,1024]
// ws: [0, 7.34M) A8 (b-major, t-pad 112) ; [7.34M, 11.53M) Bt (4 planes)

typedef __attribute__((ext_vector_type(4))) int int4v;

#define T_STEPS 100
#define T_PAD   112
#define BO      65536
#define K_DIM   1024
#define A8_OFF  0
#define BT_OFF  7340032      // 64*112*1024

// ---- prepass (R19 verbatim): spikes -> A8 (b-major, t-padded, tiled);
//               W -> Bt 4 balanced base-256 i8 planes ----
__global__ __launch_bounds__(256)
void prepass(const float* __restrict__ S, const float* __restrict__ W,
             signed char* __restrict__ A8, signed char* __restrict__ Bt) {
    const int wave = blockIdx.x * 4 + (threadIdx.x >> 6);  // 0..8191
    const int lane = threadIdx.x & 63;
    const int r16 = lane & 15, quad = lane >> 4;

    if (wave < 7168) {
        // A tile: wave = b*112 + jt*16 + k64 ; rows t = jt*16 + r16
        const int b   = wave / 112;
        const int rem = wave - b * 112;
        const int jt  = rem >> 4, k64 = rem & 15;
        const int t   = jt * 16 + r16;
        union { signed char c[16]; int4v v; } u;
        if (t < T_STEPS) {
            const float* sp = S + ((size_t)t * 64 + b) * K_DIM + k64 * 64 + quad * 16;
            const float4 s0 = *(const float4*)(sp);
            const float4 s1 = *(const float4*)(sp + 4);
            const float4 s2 = *(const float4*)(sp + 8);
            const float4 s3 = *(const float4*)(sp + 12);
            const float sv[16] = {s0.x,s0.y,s0.z,s0.w, s1.x,s1.y,s1.z,s1.w,
                                  s2.x,s2.y,s2.z,s2.w, s3.x,s3.y,s3.z,s3.w};
#pragma unroll
            for (int e = 0; e < 16; ++e) u.c[e] = (signed char)sv[e];  // exact 0/1
        } else {
#pragma unroll
            for (int e = 0; e < 16; ++e) u.c[e] = 0;                   // t-pad
        }
        *(int4v*)(A8 + (size_t)wave * 1024 + lane * 16) = u.v;
    } else {
        const int t2 = wave - 7168;                 // 0..1023
        const int n16 = t2 >> 4, k64 = t2 & 15;
        const int n = n16 * 16 + r16;
        const float* wp = W + (size_t)n * K_DIM + k64 * 64 + quad * 16;
        const float4 w0 = *(const float4*)(wp);
        const float4 w1 = *(const float4*)(wp + 4);
        const float4 w2 = *(const float4*)(wp + 8);
        const float4 w3 = *(const float4*)(wp + 12);
        const float wv[16] = {w0.x,w0.y,w0.z,w0.w, w1.x,w1.y,w1.z,w1.w,
                              w2.x,w2.y,w2.z,w2.w, w3.x,w3.y,w3.z,w3.w};
        union { signed char c[16]; int4v v; } u[4];
#pragma unroll
        for (int e = 0; e < 16; ++e) {
            long long q = llrint((double)wv[e] * 0x1p28);   // |q| < 2^31
#pragma unroll
            for (int p = 0; p < 3; ++p) {
                const int d = (int)(((q + 128) & 255) - 128);  // [-128,127]
                u[p].c[e] = (signed char)d;
                q = (q - d) >> 8;                              // exact
            }
            u[3].c[e] = (signed char)q;                        // |d3| <= ~88
        }
        signed char* base = Bt + (size_t)(n16 * 16 + k64) * 4 * 1024 + lane * 16;
#pragma unroll
        for (int p = 0; p < 4; ++p)
            *(int4v*)(base + (size_t)p * 1024) = u[p].v;
    }
}

// ---- fused GEMM + scan, one wave per block. ----
__global__ __launch_bounds__(64, 3)
void gemm_scan(const signed char* __restrict__ A8,
               const signed char* __restrict__ Bt,
               const float* __restrict__ bias,
               const float* __restrict__ mem0,
               float* __restrict__ out) {
    __shared__ double dulds[T_STEPS * 16];       // 12800 B -> 12 blocks/CU

    const int bid = blockIdx.x;                  // 0..4095
    const int ng  = bid >> 6;                    // n16 tile 0..63
    const int b   = bid & 63;                    // batch row (same-CU waves share b's A? no:
                                                 // bid+-256 -> ng+-4, same b -> share A panel)

    const int lane = threadIdx.x & 63;
    const int quad = lane >> 4, r16 = lane & 15;

    // fragment bases (1 KB chunks, lane-linear 16B/lane)
    const signed char* abase = A8 + (size_t)b * T_PAD * 1024 + lane * 16;
    const signed char* bbase = Bt + (size_t)ng * 65536 + lane * 16;

    int4v acc[7][4] = {};

    for (int kt = 0; kt < 16; ++kt) {
        int4v af[7], bf[4];
#pragma unroll
        for (int i = 0; i < 7; ++i)
            af[i] = *(const int4v*)(abase + (size_t)(i * 16 + kt) * 1024);
#pragma unroll
        for (int p = 0; p < 4; ++p)
            bf[p] = *(const int4v*)(bbase + (size_t)(kt * 4 + p) * 1024);
#pragma unroll
        for (int p = 0; p < 4; ++p)
#pragma unroll
            for (int i = 0; i < 7; ++i)
                acc[i][p] = __builtin_amdgcn_mfma_i32_16x16x64_i8(
                    af[i], bf[p], acc[i][p], 0, 0, 0);
    }

    // exact i64 Horner -> f64 du -> LDS transpose (row t, col r16)
    const double bd = (double)bias[ng * 16 + r16];
#pragma unroll
    for (int i = 0; i < 7; ++i)
#pragma unroll
        for (int e = 0; e < 4; ++e) {
            const int t = i * 16 + quad * 4 + e;
            if (t < T_STEPS) {
                long long v = (long long)acc[i][3][e];
                v = v * 256 + (long long)acc[i][2][e];
                v = v * 256 + (long long)acc[i][1][e];
                v = v * 256 + (long long)acc[i][0][e];   // exact, |v| < 2^42
                dulds[t * 16 + r16] = (double)v * 0x1p-28 + bd;
            }
        }
    __syncthreads();   // single wave: compiles to a waitcnt, no s_barrier cost

    // membrane scan (R16 math verbatim, exact f64 du): 16 lanes, 16 columns.
    if (lane < 16) {
        const int bo = b * 1024 + ng * 16 + lane;
        double m = (double)mem0[bo];
        double cnt = 0.0;
        double d[4];
#pragma unroll
        for (int u = 0; u < 4; ++u) d[u] = dulds[u * 16 + lane];
        for (int g = 0; g < 25; ++g) {
            double dn[4];
            if (g + 1 < 25) {
#pragma unroll
                for (int u = 0; u < 4; ++u) dn[u] = dulds[((g + 1) * 4 + u) * 16 + lane];
            }
#pragma unroll
            for (int u = 0; u < 4; ++u) {
                m += d[u];
                const double s = (m > 15.0) ? 1.0 : 0.0;
                m = fmin(fmax(m, 0.0), 15.0);
                out[(size_t)(g * 4 + u) * BO + bo] = (float)s;
                cnt += s;
                m -= m * s;
            }
            if (g + 1 < 25) {
#pragma unroll
                for (int u = 0; u < 4; ++u) d[u] = dn[u];
            }
        }
        out[(size_t)T_STEPS * BO + bo] = (float)m;
        out[(size_t)(T_STEPS + 1) * BO + bo] = (float)(cnt * 0.01);
    }
}

extern "C" void kernel_launch(void* const* d_in, const int* in_sizes, int n_in,
                              void* d_out, int out_size, void* d_ws, size_t ws_size,
                              hipStream_t stream) {
    const float* spikes = (const float*)d_in[0];  // [100,64,1024]
    const float* mem    = (const float*)d_in[1];  // [64,1024]
    // d_in[2] = hat_spikes: dead in forward
    const float* W      = (const float*)d_in[3];  // [1024,1024]
    const float* b      = (const float*)d_in[4];  // [1024]
    float* out = (float*)d_out;
    signed char* A8 = (signed char*)d_ws + A8_OFF;
    signed char* Bt = (signed char*)d_ws + BT_OFF;

    prepass<<<dim3(2048), 256, 0, stream>>>(spikes, W, A8, Bt);
    gemm_scan<<<dim3(4096), 64, 0, stream>>>(A8, Bt, b, mem, out);
}

// Round 3
// 122.700 us; speedup vs baseline: 1.7916x; 1.7916x over previous
//
#include <hip/hip_runtime.h>

// SNNLinear, exact-trajectory i8-digit MFMA. Round 21 = R20 spill fix.
// R20 post-mortem: __launch_bounds__(64,3) capped VGPRs at ~170 but the
// kernel needs ~200 -> compiler spilled acc[7][4] to scratch INSIDE the
// MFMA loop (VGPR_Count=84 < 112 accs; WRITE_SIZE 322 MB of scratch
// traffic; 146us, MfmaUtil 8%). R21: __launch_bounds__(64,2) -> 256-VGPR
// budget, no spill, 2 waves/SIMD = 8 independent 1-wave blocks/CU
// (LDS 8x12.8 KB = 102 KB fits). Structure unchanged from R20:
//   - one WAVE per block = (b, n16): 112m x 16n x 1024k x 4 planes,
//     fragments loaded directly global->VGPR (A8/Bt fragment-tiled,
//     1 KB chunk = one lane-linear wave fragment), zero barriers.
//   - bid = ng*64 + b keeps bid%8 = b%8: each XCD's L2 holds its 8 A
//     panels (0.9 MB) + Bt (4.2 MB) ~resident.
//   - scan tail of each wave overlaps 7 other waves' MFMA phases.
// Math identical to R19/R20 (passed): exact 0/1 A, 4 balanced base-256 i8
// planes of round(W*2^28), mfma_i32_16x16x64_i8 exact, i64 Horner ->
// exact f64 du -> f64 scan verbatim.
// Outputs: ss[100,64,1024] | mem_out[64,1024] | hat_s[64,1024]
// ws: [0, 7.34M) A8 (b-major, t-pad 112) ; [7.34M, 11.53M) Bt (4 planes)

typedef __attribute__((ext_vector_type(4))) int int4v;

#define T_STEPS 100
#define T_PAD   112
#define BO      65536
#define K_DIM   1024
#define A8_OFF  0
#define BT_OFF  7340032      // 64*112*1024

// ---- prepass (R19 verbatim): spikes -> A8 (b-major, t-padded, tiled);
//               W -> Bt 4 balanced base-256 i8 planes ----
__global__ __launch_bounds__(256)
void prepass(const float* __restrict__ S, const float* __restrict__ W,
             signed char* __restrict__ A8, signed char* __restrict__ Bt) {
    const int wave = blockIdx.x * 4 + (threadIdx.x >> 6);  // 0..8191
    const int lane = threadIdx.x & 63;
    const int r16 = lane & 15, quad = lane >> 4;

    if (wave < 7168) {
        // A tile: wave = b*112 + jt*16 + k64 ; rows t = jt*16 + r16
        const int b   = wave / 112;
        const int rem = wave - b * 112;
        const int jt  = rem >> 4, k64 = rem & 15;
        const int t   = jt * 16 + r16;
        union { signed char c[16]; int4v v; } u;
        if (t < T_STEPS) {
            const float* sp = S + ((size_t)t * 64 + b) * K_DIM + k64 * 64 + quad * 16;
            const float4 s0 = *(const float4*)(sp);
            const float4 s1 = *(const float4*)(sp + 4);
            const float4 s2 = *(const float4*)(sp + 8);
            const float4 s3 = *(const float4*)(sp + 12);
            const float sv[16] = {s0.x,s0.y,s0.z,s0.w, s1.x,s1.y,s1.z,s1.w,
                                  s2.x,s2.y,s2.z,s2.w, s3.x,s3.y,s3.z,s3.w};
#pragma unroll
            for (int e = 0; e < 16; ++e) u.c[e] = (signed char)sv[e];  // exact 0/1
        } else {
#pragma unroll
            for (int e = 0; e < 16; ++e) u.c[e] = 0;                   // t-pad
        }
        *(int4v*)(A8 + (size_t)wave * 1024 + lane * 16) = u.v;
    } else {
        const int t2 = wave - 7168;                 // 0..1023
        const int n16 = t2 >> 4, k64 = t2 & 15;
        const int n = n16 * 16 + r16;
        const float* wp = W + (size_t)n * K_DIM + k64 * 64 + quad * 16;
        const float4 w0 = *(const float4*)(wp);
        const float4 w1 = *(const float4*)(wp + 4);
        const float4 w2 = *(const float4*)(wp + 8);
        const float4 w3 = *(const float4*)(wp + 12);
        const float wv[16] = {w0.x,w0.y,w0.z,w0.w, w1.x,w1.y,w1.z,w1.w,
                              w2.x,w2.y,w2.z,w2.w, w3.x,w3.y,w3.z,w3.w};
        union { signed char c[16]; int4v v; } u[4];
#pragma unroll
        for (int e = 0; e < 16; ++e) {
            long long q = llrint((double)wv[e] * 0x1p28);   // |q| < 2^31
#pragma unroll
            for (int p = 0; p < 3; ++p) {
                const int d = (int)(((q + 128) & 255) - 128);  // [-128,127]
                u[p].c[e] = (signed char)d;
                q = (q - d) >> 8;                              // exact
            }
            u[3].c[e] = (signed char)q;                        // |d3| <= ~88
        }
        signed char* base = Bt + (size_t)(n16 * 16 + k64) * 4 * 1024 + lane * 16;
#pragma unroll
        for (int p = 0; p < 4; ++p)
            *(int4v*)(base + (size_t)p * 1024) = u[p].v;
    }
}

// ---- fused GEMM + scan, one wave per block. ----
__global__ __launch_bounds__(64, 2)
void gemm_scan(const signed char* __restrict__ A8,
               const signed char* __restrict__ Bt,
               const float* __restrict__ bias,
               const float* __restrict__ mem0,
               float* __restrict__ out) {
    __shared__ double dulds[T_STEPS * 16];       // 12800 B

    const int bid = blockIdx.x;                  // 0..4095
    const int ng  = bid >> 6;                    // n16 tile 0..63
    const int b   = bid & 63;                    // batch row; bid%8 = b%8 -> XCD locality

    const int lane = threadIdx.x & 63;
    const int quad = lane >> 4, r16 = lane & 15;

    // fragment bases (1 KB chunks, lane-linear 16B/lane)
    const signed char* abase = A8 + (size_t)b * T_PAD * 1024 + lane * 16;
    const signed char* bbase = Bt + (size_t)ng * 65536 + lane * 16;

    int4v acc[7][4] = {};

    for (int kt = 0; kt < 16; ++kt) {
        int4v af[7], bf[4];
#pragma unroll
        for (int i = 0; i < 7; ++i)
            af[i] = *(const int4v*)(abase + (size_t)(i * 16 + kt) * 1024);
#pragma unroll
        for (int p = 0; p < 4; ++p)
            bf[p] = *(const int4v*)(bbase + (size_t)(kt * 4 + p) * 1024);
#pragma unroll
        for (int p = 0; p < 4; ++p)
#pragma unroll
            for (int i = 0; i < 7; ++i)
                acc[i][p] = __builtin_amdgcn_mfma_i32_16x16x64_i8(
                    af[i], bf[p], acc[i][p], 0, 0, 0);
    }

    // exact i64 Horner -> f64 du -> LDS transpose (row t, col r16)
    const double bd = (double)bias[ng * 16 + r16];
#pragma unroll
    for (int i = 0; i < 7; ++i)
#pragma unroll
        for (int e = 0; e < 4; ++e) {
            const int t = i * 16 + quad * 4 + e;
            if (t < T_STEPS) {
                long long v = (long long)acc[i][3][e];
                v = v * 256 + (long long)acc[i][2][e];
                v = v * 256 + (long long)acc[i][1][e];
                v = v * 256 + (long long)acc[i][0][e];   // exact, |v| < 2^42
                dulds[t * 16 + r16] = (double)v * 0x1p-28 + bd;
            }
        }
    __syncthreads();   // single wave: compiles to a waitcnt, no scheduling cost

    // membrane scan (R16 math verbatim, exact f64 du): 16 lanes, 16 columns.
    if (lane < 16) {
        const int bo = b * 1024 + ng * 16 + lane;
        double m = (double)mem0[bo];
        double cnt = 0.0;
        double d[4];
#pragma unroll
        for (int u = 0; u < 4; ++u) d[u] = dulds[u * 16 + lane];
        for (int g = 0; g < 25; ++g) {
            double dn[4];
            if (g + 1 < 25) {
#pragma unroll
                for (int u = 0; u < 4; ++u) dn[u] = dulds[((g + 1) * 4 + u) * 16 + lane];
            }
#pragma unroll
            for (int u = 0; u < 4; ++u) {
                m += d[u];
                const double s = (m > 15.0) ? 1.0 : 0.0;
                m = fmin(fmax(m, 0.0), 15.0);
                out[(size_t)(g * 4 + u) * BO + bo] = (float)s;
                cnt += s;
                m -= m * s;
            }
            if (g + 1 < 25) {
#pragma unroll
                for (int u = 0; u < 4; ++u) d[u] = dn[u];
            }
        }
        out[(size_t)T_STEPS * BO + bo] = (float)m;
        out[(size_t)(T_STEPS + 1) * BO + bo] = (float)(cnt * 0.01);
    }
}

extern "C" void kernel_launch(void* const* d_in, const int* in_sizes, int n_in,
                              void* d_out, int out_size, void* d_ws, size_t ws_size,
                              hipStream_t stream) {
    const float* spikes = (const float*)d_in[0];  // [100,64,1024]
    const float* mem    = (const float*)d_in[1];  // [64,1024]
    // d_in[2] = hat_spikes: dead in forward
    const float* W      = (const float*)d_in[3];  // [1024,1024]
    const float* b      = (const float*)d_in[4];  // [1024]
    float* out = (float*)d_out;
    signed char* A8 = (signed char*)d_ws + A8_OFF;
    signed char* Bt = (signed char*)d_ws + BT_OFF;

    prepass<<<dim3(2048), 256, 0, stream>>>(spikes, W, A8, Bt);
    gemm_scan<<<dim3(4096), 64, 0, stream>>>(A8, Bt, b, mem, out);
}